// Round 13
// baseline (473.570 us; speedup 1.0000x reference)
//
#include <hip/hip_runtime.h>
#include <hip/hip_bf16.h>
#include <math.h>

#define D_MODEL 2048
#define N_HEADS 16
#define D_HEAD  128
#define BATCH   64
#define SEQ     128
#define BT      (BATCH*SEQ)   // 8192 rows
#define LDF     6144          // fused QKV row stride
#define KOFF    2048
#define VOFF    4096

typedef __bf16 bf16;
typedef __attribute__((ext_vector_type(8))) __bf16 bf16x8;
typedef __attribute__((ext_vector_type(4))) float  f32x4;

__device__ __forceinline__ f32x4 mfma16(bf16x8 a, bf16x8 b, f32x4 c) {
    return __builtin_amdgcn_mfma_f32_16x16x32_bf16(a, b, c, 0, 0, 0);
}

__device__ __forceinline__ bf16x8 cvt8_f32(const float* p) {
    f32x4 lo = *(const f32x4*)p;
    f32x4 hi = *(const f32x4*)(p + 4);
    bf16x8 r;
    r[0] = (bf16)lo[0]; r[1] = (bf16)lo[1]; r[2] = (bf16)lo[2]; r[3] = (bf16)lo[3];
    r[4] = (bf16)hi[0]; r[5] = (bf16)hi[1]; r[6] = (bf16)hi[2]; r[7] = (bf16)hi[3];
    return r;
}

// async global->LDS, 16 B/lane; LDS dest = wave-uniform base + lane*16 (m104)
__device__ __forceinline__ void gl2lds16(const bf16* g, bf16* l) {
    __builtin_amdgcn_global_load_lds(
        (const __attribute__((address_space(1))) void*)g,
        (__attribute__((address_space(3))) void*)l, 16, 0, 0);
}

// table-driven rope: tb -> 4 consecutive (cos,sin) fp32 pairs (32B, 16B-aligned)
__device__ __forceinline__ bf16x8 rope8t(bf16x8 v, const float* tb) {
    f32x4 p0 = *(const f32x4*)tb;        // c0,s0,c1,s1
    f32x4 p1 = *(const f32x4*)(tb + 4);  // c2,s2,c3,s3
    bf16x8 r;
    { float e=(float)v[0], o=(float)v[1];
      r[0]=(bf16)(e*p0[0]-o*p0[1]); r[1]=(bf16)(e*p0[1]+o*p0[0]); }
    { float e=(float)v[2], o=(float)v[3];
      r[2]=(bf16)(e*p0[2]-o*p0[3]); r[3]=(bf16)(e*p0[3]+o*p0[2]); }
    { float e=(float)v[4], o=(float)v[5];
      r[4]=(bf16)(e*p1[0]-o*p1[1]); r[5]=(bf16)(e*p1[1]+o*p1[0]); }
    { float e=(float)v[6], o=(float)v[7];
      r[6]=(bf16)(e*p1[2]-o*p1[3]); r[7]=(bf16)(e*p1[3]+o*p1[2]); }
    return r;
}

// ---------------------------------------------------------------------------
// rope table init: tab[(t*64+i)] = {cos(t*theta_i), sin(t*theta_i)}, 64 KB.
// Same __expf/__sincosf math as the old in-kernel rope -> identical numerics.
// ---------------------------------------------------------------------------
__global__ __launch_bounds__(256) void rope_tab(float* __restrict__ tab)
{
    int idx = blockIdx.x * 256 + threadIdx.x;   // < 8192 = 128 pos x 64 pairs
    int t = idx >> 6, i = idx & 63;
    float theta = __expf((float)(2 * i) * (-9.210340371976184f / 128.0f));
    float sn, cs;
    __sincosf((float)t * theta, &sn, &cs);
    tab[idx * 2]     = cs;
    tab[idx * 2 + 1] = sn;
}

// ---------------------------------------------------------------------------
__global__ __launch_bounds__(256) void cvt_kernel(const float* __restrict__ src,
                                                  bf16* __restrict__ dst, int n8)
{
    int i = blockIdx.x * 256 + threadIdx.x;
    if (i < n8) *(bf16x8*)(dst + (size_t)i * 8) = cvt8_f32(src + (size_t)i * 8);
}

__global__ __launch_bounds__(256) void cvt_w3(const float* __restrict__ w0,
                                              const float* __restrict__ w1,
                                              const float* __restrict__ w2,
                                              bf16* __restrict__ dst)
{
    int i   = blockIdx.x * 256 + threadIdx.x;     // < 3*2^19
    int sel = i >> 19;
    int off = i & ((1 << 19) - 1);
    const float* s = (sel == 0) ? w0 : (sel == 1) ? w1 : w2;
    *(bf16x8*)(dst + (size_t)i * 8) = cvt8_f32(s + (size_t)off * 8);
}

// ---------------------------------------------------------------------------
// gemm256: UNCHANGED from r9 (best measured: ~206 us QKV, MfmaUtil 44.5%).
// Schedule family converged at 44% across r1/r3/r7/r9 variants — frozen.
// ---------------------------------------------------------------------------

#define BAR() __builtin_amdgcn_s_barrier()
#define SB0() __builtin_amdgcn_sched_barrier(0)
#define WAIT_LGKM0() asm volatile("s_waitcnt lgkmcnt(0)" ::: "memory")

#define READ_A(BSEL, mh) do {                                                 \
    _Pragma("unroll") for (int ii = 0; ii < 4; ++ii)                          \
    _Pragma("unroll") for (int kk = 0; kk < 2; ++kk)                          \
        Af[ii][kk] = *(const bf16x8*)&As[BSEL][aoff[(mh)*4+ii] + ksw[kk]];    \
    } while (0)

#define READ_B(BSEL, j0) do {                                                 \
    _Pragma("unroll") for (int jj = 0; jj < 2; ++jj)                          \
    _Pragma("unroll") for (int kk = 0; kk < 2; ++kk)                          \
        Bf[(j0)+jj][kk] = *(const bf16x8*)&Bs[BSEL][bof[(j0)+jj] + ksw[kk]];  \
    } while (0)

#define MQ(i0, j0) do {                                                       \
    __builtin_amdgcn_s_setprio(1);                                            \
    _Pragma("unroll") for (int ii = 0; ii < 4; ++ii)                          \
    _Pragma("unroll") for (int jj = 0; jj < 2; ++jj)                          \
    _Pragma("unroll") for (int kk = 0; kk < 2; ++kk)                          \
        acc[(i0)+ii][(j0)+jj] =                                               \
            mfma16(Af[ii][kk], Bf[(j0)+jj][kk], acc[(i0)+ii][(j0)+jj]);       \
    __builtin_amdgcn_s_setprio(0);                                            \
    } while (0)

#define STG1(BSEL, tt, c) do {                                                \
    if ((c) < 4)                                                              \
        gl2lds16(Ag + (size_t)(c) * 64 * lda + (size_t)(tt) * 64,             \
                 &As[BSEL][(c) * 4096 + w * 512]);                            \
    else                                                                      \
        gl2lds16(Bg + (size_t)((c) - 4) * 64 * ldb + (size_t)(tt) * 64,       \
                 &Bs[BSEL][((c) - 4) * 4096 + w * 512]);                      \
    } while (0)

#define TILE_ITER(BSEL, OSEL, tt, MODE) do {                                  \
    READ_A(BSEL, 0); READ_B(BSEL, 0);                                         \
    if (MODE < 2) { STG1(OSEL, (tt) + 1, 2); STG1(OSEL, (tt) + 1, 3); }       \
    SB0(); BAR(); WAIT_LGKM0(); SB0();                                        \
    MQ(0, 0);                                                                 \
    SB0(); BAR();                                                             \
    READ_B(BSEL, 2);                                                          \
    if (MODE < 2) { STG1(OSEL, (tt) + 1, 4); STG1(OSEL, (tt) + 1, 5); }       \
    SB0(); BAR(); WAIT_LGKM0(); SB0();                                        \
    MQ(0, 2);                                                                 \
    SB0(); BAR();                                                             \
    READ_A(BSEL, 1);                                                          \
    if (MODE < 2) { STG1(OSEL, (tt) + 1, 6); STG1(OSEL, (tt) + 1, 7); }       \
    SB0(); BAR(); WAIT_LGKM0(); SB0();                                        \
    MQ(4, 2);                                                                 \
    SB0(); BAR();                                                             \
    if (MODE == 0) { STG1(BSEL, (tt) + 2, 0); STG1(BSEL, (tt) + 2, 1); }      \
    SB0(); BAR(); SB0();                                                      \
    MQ(4, 0);                                                                 \
    if (MODE == 0) asm volatile("s_waitcnt vmcnt(2)" ::: "memory");           \
    if (MODE == 1) asm volatile("s_waitcnt vmcnt(0)" ::: "memory");           \
    SB0(); BAR(); } while (0)

template<typename OutT>
__global__ __launch_bounds__(512, 2) void gemm256(const bf16* __restrict__ A,
                                                  const bf16* __restrict__ B,
                                                  OutT* __restrict__ C,
                                                  int lda, int ldb, int ldc,
                                                  int K, int gx)
{
    __shared__ __align__(16) bf16 As[2][16384];   // 2 x 32 KB
    __shared__ __align__(16) bf16 Bs[2][16384];   // 2 x 32 KB  (128 KB total)

    const int tid  = threadIdx.x;
    const int w    = tid >> 6;        // wave 0..7
    const int l    = tid & 63;
    const int quad = l >> 4;
    const int ln   = l & 15;
    const int wm   = w >> 2;          // 0..1
    const int wn   = w & 3;           // 0..3

    // T1: chunked XCD swizzle (gridDim.x % 8 == 0 -> bijective)
    const int nwg = gridDim.x;
    const int bid = blockIdx.x;
    const int swz = (bid & 7) * (nwg >> 3) + (bid >> 3);
    const int bx  = swz % gx;
    const int by  = swz / gx;
    const size_t mbase = (size_t)by * 256;
    const size_t nbase = (size_t)bx * 256;

    const int srow   = tid >> 3;                  // 0..63
    const int schunk = (tid & 7) ^ (srow & 7);
    const bf16* Ag = A + (mbase + srow) * (size_t)lda + schunk * 8;
    const bf16* Bg = B + (nbase + srow) * (size_t)ldb + schunk * 8;

    const int xr = ln & 7;
    int aoff[8], bof[4], ksw[2];
#pragma unroll
    for (int i = 0; i < 8; ++i) aoff[i] = (wm * 128 + i * 16 + ln) * 64;
#pragma unroll
    for (int j = 0; j < 4; ++j) bof[j]  = (wn * 64  + j * 16 + ln) * 64;
#pragma unroll
    for (int kk = 0; kk < 2; ++kk) ksw[kk] = ((kk * 4 + quad) ^ xr) * 8;

    f32x4 acc[8][4];
#pragma unroll
    for (int i = 0; i < 8; ++i)
#pragma unroll
        for (int j = 0; j < 4; ++j) acc[i][j] = (f32x4){0.f, 0.f, 0.f, 0.f};

    bf16x8 Af[4][2];
    bf16x8 Bf[4][2];

    STG1(0, 0, 0); STG1(0, 0, 1); STG1(0, 0, 2); STG1(0, 0, 3);
    STG1(0, 0, 4); STG1(0, 0, 5); STG1(0, 0, 6); STG1(0, 0, 7);
    STG1(1, 1, 0); STG1(1, 1, 1);
    asm volatile("s_waitcnt vmcnt(2)" ::: "memory");   // tile0 landed
    BAR();

    const int NT = K >> 6;            // 32 for K=2048
    int t = 0;
#pragma unroll 1
    for (; t < NT - 2; t += 2) {
        TILE_ITER(0, 1, t, 0);
        TILE_ITER(1, 0, t + 1, 0);
    }
    TILE_ITER(0, 1, NT - 2, 1);
    TILE_ITER(1, 0, NT - 1, 2);

    // C/D: col = ln, row = quad*4 + r  (m89/m91-verified)
#pragma unroll
    for (int i = 0; i < 8; ++i)
#pragma unroll
        for (int j = 0; j < 4; ++j)
#pragma unroll
            for (int r = 0; r < 4; ++r) {
                size_t row = mbase + wm * 128 + i * 16 + quad * 4 + r;
                size_t col = nbase + wn * 64 + j * 16 + ln;
                C[row * (size_t)ldc + col] = (OutT)acc[i][j][r];
            }
}

#undef BAR
#undef SB0
#undef WAIT_LGKM0
#undef READ_A
#undef READ_B
#undef MQ
#undef STG1
#undef TILE_ITER

// ---------------------------------------------------------------------------
// Attention over fused buffer. RoPE via precomputed (cos,sin) table (r10:
// replaces 64 expf + 64 sincosf per thread — the trans-pipe bottleneck —
// with 16B L2-resident loads). One workgroup per (b,h).
// ---------------------------------------------------------------------------
__global__ __launch_bounds__(256) void attn_kernel(bf16* __restrict__ buf,
                                                   const float* __restrict__ rt)
{
    __shared__ __align__(16) bf16 KP_lds[128 * 136];  // roped K, then P
    __shared__ __align__(16) bf16 Vt_lds[128 * 136];  // Vt[d][k] = V[k][d]

    const int bh = blockIdx.x;
    const int b  = bh >> 4;
    const int h  = bh & 15;
    const size_t baseQ = (size_t)b * SEQ * LDF + (size_t)h * D_HEAD;
    const size_t baseK = baseQ + KOFF;
    const size_t baseV = baseQ + VOFF;

    const int tid  = threadIdx.x;
    const int w    = tid >> 6;
    const int l    = tid & 63;
    const int quad = l >> 4;
    const int ln   = l & 15;

    // ---- stage roped K rows + V^T: thread -> row k=tid>>1, half d0=(tid&1)*64
    {
        int k  = tid >> 1;
        int d0 = (tid & 1) * 64;
        const bf16* kp = buf + baseK + (size_t)k * LDF + d0;
        const bf16* vp = buf + baseV + (size_t)k * LDF + d0;
        const float* tk = rt + ((size_t)k * 64 + d0 / 2) * 2;
        for (int c = 0; c < 8; ++c) {
            bf16x8 kv = *(const bf16x8*)(kp + c * 8);
            *(bf16x8*)&KP_lds[k * 136 + d0 + c * 8] = rope8t(kv, tk + c * 8);
            bf16x8 vv = *(const bf16x8*)(vp + c * 8);
            for (int j = 0; j < 8; ++j)
                Vt_lds[(d0 + c * 8 + j) * 136 + k] = vv[j];
        }
    }
    __syncthreads();

    const float rscale = 0.08838834764831845f;   // 1/sqrt(128)
    const float NEG    = -1e30f;

    // ---- phase 1: S = ropeQ @ ropeK^T for both strips, softmax in regs ----
    f32x4 acc2[2][8];
    for (int s = 0; s < 2; ++s)
        for (int nt = 0; nt < 8; ++nt) acc2[s][nt] = (f32x4){0.f, 0.f, 0.f, 0.f};

    for (int s = 0; s < 2; ++s) {
        const int q0 = w * 32 + s * 16;
        const float* tq = rt + (size_t)(q0 + ln) * 128;   // row stride 64 pairs
        for (int kt = 0; kt < 4; ++kt) {
            bf16x8 qa = *(const bf16x8*)(buf + baseQ + (size_t)(q0 + ln) * LDF
                                           + kt * 32 + quad * 8);
            bf16x8 a = rope8t(qa, tq + (kt * 16 + quad * 4) * 2);
            for (int nt = 0; nt < 8; ++nt) {
                bf16x8 bb = *(const bf16x8*)&KP_lds[(nt * 16 + ln) * 136
                                                    + kt * 32 + quad * 8];
                acc2[s][nt] = mfma16(a, bb, acc2[s][nt]);
            }
        }

        float mx[4] = {NEG, NEG, NEG, NEG};
        for (int nt = 0; nt < 8; ++nt)
            for (int r = 0; r < 4; ++r) {
                int q = q0 + quad * 4 + r;
                int c = nt * 16 + ln;
                float v = acc2[s][nt][r] * rscale;
                v = (c <= q) ? v : NEG;
                acc2[s][nt][r] = v;
                mx[r] = fmaxf(mx[r], v);
            }
        for (int m = 1; m < 16; m <<= 1)
            for (int r = 0; r < 4; ++r)
                mx[r] = fmaxf(mx[r], __shfl_xor(mx[r], m));

        float sm[4] = {0.f, 0.f, 0.f, 0.f};
        for (int nt = 0; nt < 8; ++nt)
            for (int r = 0; r < 4; ++r) {
                float p = __expf(acc2[s][nt][r] - mx[r]);
                acc2[s][nt][r] = p;
                sm[r] += p;
            }
        for (int m = 1; m < 16; m <<= 1)
            for (int r = 0; r < 4; ++r)
                sm[r] += __shfl_xor(sm[r], m);

        for (int r = 0; r < 4; ++r) sm[r] = 1.0f / sm[r];
        for (int nt = 0; nt < 8; ++nt)
            for (int r = 0; r < 4; ++r)
                acc2[s][nt][r] *= sm[r];
    }

    __syncthreads();   // all K reads from KP_lds complete

    // ---- write P over the K region (own-wave rows only) ----
    for (int s = 0; s < 2; ++s)
        for (int nt = 0; nt < 8; ++nt)
            for (int r = 0; r < 4; ++r) {
                int q = w * 32 + s * 16 + quad * 4 + r;
                int c = nt * 16 + ln;
                KP_lds[q * 136 + c] = (bf16)acc2[s][nt][r];
            }

    // ---- phase 2: O = P @ V ----
    f32x4 o[2][8];
    for (int s = 0; s < 2; ++s)
        for (int nt = 0; nt < 8; ++nt) o[s][nt] = (f32x4){0.f, 0.f, 0.f, 0.f};

    for (int kt = 0; kt < 4; ++kt) {
        bf16x8 a0 = *(const bf16x8*)&KP_lds[(w * 32 +      ln) * 136 + kt * 32 + quad * 8];
        bf16x8 a1 = *(const bf16x8*)&KP_lds[(w * 32 + 16 + ln) * 136 + kt * 32 + quad * 8];
        for (int nt = 0; nt < 8; ++nt) {
            bf16x8 bb = *(const bf16x8*)&Vt_lds[(nt * 16 + ln) * 136 + kt * 32 + quad * 8];
            o[0][nt] = mfma16(a0, bb, o[0][nt]);
            o[1][nt] = mfma16(a1, bb, o[1][nt]);
        }
    }

    for (int s = 0; s < 2; ++s)
        for (int nt = 0; nt < 8; ++nt)
            for (int r = 0; r < 4; ++r) {
                int q = w * 32 + s * 16 + quad * 4 + r;
                int d = nt * 16 + ln;
                buf[baseQ + (size_t)q * LDF + d] = (bf16)o[s][nt][r];
            }
}

// ---------------------------------------------------------------------------
extern "C" void kernel_launch(void* const* d_in, const int* in_sizes, int n_in,
                              void* d_out, int out_size, void* d_ws, size_t ws_size,
                              hipStream_t stream)
{
    const float* x  = (const float*)d_in[0];
    const float* Wq = (const float*)d_in[1];
    const float* Wk = (const float*)d_in[2];
    const float* Wv = (const float*)d_in[3];
    const float* Wo = (const float*)d_in[4];
    float* out = (float*)d_out;

    // ws layout (bf16 elems): QKV 100.7 MB | xb 33.6 MB (WoB reuses) |
    //                         WB 25.2 MB | rope table 64 KB (fp32)
    bf16*  QKV   = (bf16*)d_ws;
    bf16*  xb    = QKV + (size_t)BT * LDF;
    bf16*  WB    = xb + (size_t)BT * D_MODEL;
    float* ropeT = (float*)(WB + (size_t)3 * D_MODEL * D_MODEL);
    bf16*  WoB   = xb;                            // free after QKV GEMM

    const int n8x = BT * D_MODEL / 8;             // 2,097,152
    const int n8w = D_MODEL * D_MODEL / 8;        //   524,288 = 2^19

    rope_tab<<<32, 256, 0, stream>>>(ropeT);
    cvt_kernel<<<(n8x + 255) / 256, 256, 0, stream>>>(x, xb, n8x);
    cvt_w3<<<(3 * n8w) / 256, 256, 0, stream>>>(Wq, Wk, Wv, WB);

    // fused QKV projection: [8192 x 6144] = xb @ WB^T  (768 blocks, %8==0)
    gemm256<bf16><<<dim3((LDF / 256) * (BT / 256)), 512, 0, stream>>>(
        xb, WB, QKV, D_MODEL, D_MODEL, LDF, D_MODEL, LDF / 256);

    cvt_kernel<<<(n8w + 255) / 256, 256, 0, stream>>>(Wo, WoB, n8w);

    // attention with table-driven RoPE; O in-place over Q columns
    attn_kernel<<<BATCH * N_HEADS, 256, 0, stream>>>(QKV, ropeT);

    // output projection: out[8192 x 2048] = O @ Wo^T (fp32 out, 256 blocks)
    gemm256<float><<<dim3((D_MODEL / 256) * (BT / 256)), 512, 0, stream>>>(
        QKV, WoB, out, LDF, D_MODEL, D_MODEL, D_MODEL, D_MODEL / 256);
}